// Round 7
// baseline (945.087 us; speedup 1.0000x reference)
//
#include <hip/hip_runtime.h>
#include <cstdint>
#include <cstddef>

#define MROWS 200            // T*C real rows
#define PM    224            // padded rows: 14 frag-rows of 16 (>= 200)
#define KDIM  16384          // H*W
#define DDIM  8192           // hypervector dim
#define KSL   8              // k slices (grid.x); XCD = ks
#define KPER  (KDIM / KSL)   // 2048
#define BK    32
#define NSTEP (KPER / BK)    // 64 K-steps per block

typedef __bf16 bf16x8 __attribute__((ext_vector_type(8)));
typedef float  f32x4  __attribute__((ext_vector_type(4)));

static __device__ __forceinline__ unsigned short f2bf_rne(float f) {
    unsigned int u = __float_as_uint(f);
    unsigned int r = (u + 0x7FFFu + ((u >> 16) & 1u)) >> 16;
    return (unsigned short)r;
}
static __device__ __forceinline__ float bf2f(unsigned short s) {
    return __uint_as_float(((unsigned int)s) << 16);
}

// async global->LDS, 16B per lane; LDS dest is wave-uniform base + lane*16
static __device__ __forceinline__ void gld_lds16(const unsigned short* g,
                                                 unsigned short* l) {
    __builtin_amdgcn_global_load_lds(
        (const __attribute__((address_space(1))) unsigned int*)g,
        (__attribute__((address_space(3))) unsigned int*)l, 16, 0, 0);
}

// ---------------------------------------------------------------------------
// Prep: split hist fp32 -> (hi, lo) bf16 planes once. Rows [200,224) zeroed.
// 16B granules stored pre-swizzled within each 64B chunk (g ^= (m>>1)&3) so
// gemm's global_load_lds dest stays linear while frag reads de-swizzle.
// Replay-safe ws use: fully rewritten from inputs every launch.
// ---------------------------------------------------------------------------
__global__ __launch_bounds__(256) void prep_kernel(const float* __restrict__ hist,
                                                   unsigned short* __restrict__ ahi,
                                                   unsigned short* __restrict__ alo) {
    const int g  = blockIdx.x * 256 + threadIdx.x;   // granule id, < PM*2048
    const int m  = g >> 11;                          // 2048 granules per row
    const int gc = g & 2047;
    const int f  = (m >> 1) & 3;
    const int sgc = (gc & ~3) | ((gc & 3) ^ f);      // swizzled source granule
    alignas(16) unsigned short hi[8], lo[8];
    if (m < MROWS) {
        const float* src = hist + (size_t)m * KDIM + sgc * 8;
        float4 a = *(const float4*)(src);
        float4 b = *(const float4*)(src + 4);
        const float v[8] = {a.x, a.y, a.z, a.w, b.x, b.y, b.z, b.w};
#pragma unroll
        for (int i = 0; i < 8; ++i) {
            unsigned short h = f2bf_rne(v[i]);
            hi[i] = h;
            lo[i] = f2bf_rne(v[i] - bf2f(h));        // exact residual
        }
    } else {
#pragma unroll
        for (int i = 0; i < 8; ++i) { hi[i] = 0; lo[i] = 0; }
    }
    *(uint4*)(ahi + (size_t)g * 8) = *(const uint4*)hi;
    *(uint4*)(alo + (size_t)g * 8) = *(const uint4*)lo;
}

// ---------------------------------------------------------------------------
// Fused GEMM + bind-reduce. R7: PLANE-SPLIT BLOCKS for 3 blocks/CU.
// r5 measured g~=159us = ~2x the max single-pipe demand (HBM 3200 cyc/round,
// LDS 2300, MFMA 544/SIMD) -> ~2700 cyc/round of serialization that 2
// blocks/CU can't cover; r6 (more waves/block) made it worse. This round:
// each block handles ONE bf16 plane (hi or lo) of A. LDS halves to 49.7KB
// -> 3 blocks/CU, 3 independent barrier domains/SIMD; per-step serial chain
// halves (28 MFMA, 11 ds_reads/wave). B is logically read twice (hi+lo
// twins), but twins are dispatch-adjacent (grid y = 2*nb+pl) on the same
// XCD (= ks), so the second read should hit the 4MB L2 -> HBM B stays
// ~512MB. br is 1-deep: B(kk+1) issued mid-step kk, packed top of kk+1
// (~0.7 step = ~2000cyc cover >> 900cy HBM latency) -> plain __syncthreads
// (vmcnt-0 drain) is free; no asm ledger needed. acc[7][4]=112 VGPR;
// __launch_bounds__(256,3) forces the ~168-VGPR cap for 3 waves/SIMD.
// Step kk: pack Bs[u]<-br; sync; issue A(kk+1)->As[u^1]; issue B(kk+1)->br;
//          fb/fa ds_reads; 28 MFMA (setprio). Tail issues wrap (dummy).
// hi/lo sums land in separate fp32 partials, reduced by sign_reduce (fp32
// reorder vs r5 — same class of reordering as any KSL change).
// ---------------------------------------------------------------------------
__global__ __launch_bounds__(256, 3)
void gemm_kernel(const unsigned short* __restrict__ ahi,
                 const unsigned short* __restrict__ alo,
                 const float* __restrict__ pos,
                 const float* __restrict__ time_w,
                 const float* __restrict__ pol_w,
                 float* __restrict__ partials) {
    __shared__ alignas(16) unsigned short As[2][PM * BK];  // dbuf, one plane 28.7KB
    __shared__ alignas(16) unsigned short Bs[2][128][40];  // dbuf, +8 pad 20.5KB
    __shared__ float sPart[128];

    const int t     = threadIdx.x;             // 0..255
    const int ks    = blockIdx.x;              // XCD = ks
    const int nb    = blockIdx.y >> 1;         // n-block 0..63
    const int pl    = blockIdx.y & 1;          // plane: 0=hi 1=lo (twins adjacent)
    const int n0    = nb * 128;
    const int kbase = ks * KPER;
    const unsigned short* __restrict__ ap = pl ? alo : ahi;

    const int lane = t & 63;
    const int wv   = t >> 6;                   // 0..3, wave grid 2m x 2n
    const int wm   = (wv & 1) * 112;           // 7 frag-rows per wave
    const int wn   = (wv >> 1) * 64;
    const int l15  = lane & 15;
    const int q8   = (lane >> 4) * 8;          // B k-granule offset
    const int qg   = (lane >> 4) ^ ((l15 >> 1) & 3);  // A de-swizzle granule

    if (t < 128) sPart[t] = 0.f;               // visible after sync of step 0

    // A chunks: 14 chunks of 16 rows (one plane); waves take 4,4,3,3.
    const int cc0 = (wv < 2) ? wv * 4 : 8 + (wv - 2) * 3;
    const int cnt = (wv < 2) ? 4 : 3;
    const int lr = lane >> 2, lg = lane & 3;   // lane -> (row-in-chunk, granule)
    const unsigned short* gA[4];
    int lAo[4];                                // LDS chunk offsets (ushorts)
#pragma unroll
    for (int i = 0; i < 4; ++i) {
        const int ch = cc0 + ((i < cnt) ? i : 0);
        gA[i]  = ap + (size_t)(ch * 16 + lr) * KDIM + kbase + lg * 8;
        lAo[i] = ch * 512;
    }

    // B map: thread -> (2 k-rows, 8 consecutive n)
    const int bk2 = (t & 15) * 2;
    const int bnb = (t >> 4) * 8;
    const float* gB0 = pos + ((size_t)kbase + bk2) * DDIM + n0 + bnb;
    const float* gB1 = gB0 + DDIM;

    f32x4 acc[7][4];
#pragma unroll
    for (int s = 0; s < 7; ++s)
#pragma unroll
        for (int j = 0; j < 4; ++j) acc[s][j] = (f32x4){0.f, 0.f, 0.f, 0.f};

    float4 br[4];                              // B regs, 1 step deep

    // ---- prologue: B(0) -> br; A(0) -> As[0] ----
    br[0] = *(const float4*)(gB0);
    br[1] = *(const float4*)(gB0 + 4);
    br[2] = *(const float4*)(gB1);
    br[3] = *(const float4*)(gB1 + 4);
    __builtin_amdgcn_sched_barrier(0);
#pragma unroll
    for (int i = 0; i < 4; ++i)
        if (i < cnt) gld_lds16(gA[i], &As[0][lAo[i]]);
    __builtin_amdgcn_sched_barrier(0);

#pragma unroll 2
    for (int kk = 0; kk < NSTEP; ++kk) {
        const int u = kk & 1;

        // ---- pack B(kk) (compiler waits its loads) into Bs[u] ----
        {
            const float xv[8] = {br[0].x, br[0].y, br[0].z, br[0].w,
                                 br[1].x, br[1].y, br[1].z, br[1].w};
            const float yv[8] = {br[2].x, br[2].y, br[2].z, br[2].w,
                                 br[3].x, br[3].y, br[3].z, br[3].w};
#pragma unroll
            for (int j = 0; j < 8; ++j) {
                unsigned int w = (__float_as_uint(xv[j]) >> 16) |
                                 (__float_as_uint(yv[j]) & 0xFFFF0000u);
                *(unsigned int*)&Bs[u][bnb + j][bk2] = w;
            }
        }
        __builtin_amdgcn_sched_barrier(0);
        __syncthreads();   // drains A(kk) DMAs + Bs[u] writes; tiles(kk) ready
        __builtin_amdgcn_sched_barrier(0);

        // ---- issue A(kk+1) into the other LDS buffer (wraps at tail) ----
        {
            const int koff = ((kk + 1) & (NSTEP - 1)) * BK;   // ushorts
#pragma unroll
            for (int i = 0; i < 4; ++i)
                if (i < cnt) gld_lds16(gA[i] + koff, &As[u ^ 1][lAo[i]]);
        }
        __builtin_amdgcn_sched_barrier(0);

        // ---- issue B(kk+1) into br (wraps at tail; ~0.7-step cover) ----
        {
            const size_t roff = (size_t)((kk + 1) & (NSTEP - 1)) * BK * DDIM;
            br[0] = *(const float4*)(gB0 + roff);
            br[1] = *(const float4*)(gB0 + roff + 4);
            br[2] = *(const float4*)(gB1 + roff);
            br[3] = *(const float4*)(gB1 + roff + 4);
        }
        __builtin_amdgcn_sched_barrier(0);

        // ---- fragments + MFMA on tiles(kk), single plane ----
        uint4 fb[4];
#pragma unroll
        for (int j = 0; j < 4; ++j)
            fb[j] = *(const uint4*)&Bs[u][wn + j * 16 + l15][q8];

        __builtin_amdgcn_s_setprio(1);
#pragma unroll
        for (int s = 0; s < 7; ++s) {
            const uint4 fa = *(const uint4*)&As[u][(wm + s * 16 + l15) * BK + qg * 8];
#pragma unroll
            for (int j = 0; j < 4; ++j)
                acc[s][j] = __builtin_amdgcn_mfma_f32_16x16x32_bf16(
                    __builtin_bit_cast(bf16x8, fa),
                    __builtin_bit_cast(bf16x8, fb[j]), acc[s][j], 0, 0, 0);
        }
        __builtin_amdgcn_s_setprio(0);
        __builtin_amdgcn_sched_barrier(0);
    }

    // Epilogue: C/D layout col = lane&15, row = (lane>>4)*4 + reg (m89/m91).
    // Block owns partial strip (ks, pl, n0..n0+127) exclusively -> plain store.
    const int qrow = (lane >> 4) * 4;
#pragma unroll
    for (int j = 0; j < 4; ++j) {
        const int col = wn + j * 16 + l15;
        const int d   = n0 + col;
        const float p0 = pol_w[d];
        const float p1 = pol_w[DDIM + d];
        float part = 0.f;
#pragma unroll
        for (int s = 0; s < 7; ++s)
#pragma unroll
            for (int r = 0; r < 4; ++r) {
                const int m = wm + s * 16 + qrow + r;
                if (m < MROWS) {               // pad rows: zero A, skip weights
                    const float w = time_w[(size_t)(m >> 1) * DDIM + d] *
                                    ((m & 1) ? p1 : p0);
                    part += w * acc[s][j][r];
                }
            }
        atomicAdd(&sPart[col], part);          // LDS-scope only (2 m-waves/col)
    }
    __syncthreads();                           // drains leftover dummy loads
    if (t < 128)
        partials[((size_t)ks * 2 + pl) * DDIM + n0 + t] = sPart[t];
}

// ---------------------------------------------------------------------------
// Final: out[d] = sign(sum over 16 strips). Writes every element of out.
// ---------------------------------------------------------------------------
__global__ __launch_bounds__(256) void sign_reduce_kernel(const float* __restrict__ partials,
                                                          float* __restrict__ out) {
    const int d = blockIdx.x * 256 + threadIdx.x;
    float s = 0.f;
#pragma unroll
    for (int k = 0; k < KSL * 2; ++k) s += partials[(size_t)k * DDIM + d];
    out[d] = (s > 0.f) ? 1.f : ((s < 0.f) ? -1.f : 0.f);
}

// ---------------------------------------------------------------------------
extern "C" void kernel_launch(void* const* d_in, const int* in_sizes, int n_in,
                              void* d_out, int out_size, void* d_ws, size_t ws_size,
                              hipStream_t stream) {
    const float* hist   = (const float*)d_in[0];   // [100,2,128,128]
    const float* time_w = (const float*)d_in[1];   // [100,8192]
    const float* pol_w  = (const float*)d_in[2];   // [2,8192]
    const float* pos_w  = (const float*)d_in[3];   // [16384,8192]
    float* out = (float*)d_out;                    // [8192]

    unsigned short* ahi = (unsigned short*)d_ws;               // 7.34 MB
    unsigned short* alo = ahi + (size_t)PM * KDIM;             // 7.34 MB
    float* partials = (float*)(alo + (size_t)PM * KDIM);       // 512 KB
    (void)in_sizes; (void)n_in; (void)out_size; (void)ws_size; // ws >= 15.2 MB

    prep_kernel<<<(PM * (KDIM / 8)) / 256, 256, 0, stream>>>(hist, ahi, alo);
    // grid y = 2*nb + pl: hi/lo twins adjacent in dispatch, same XCD (= ks)
    gemm_kernel<<<dim3(KSL, 2 * (DDIM / 128)), 256, 0, stream>>>(
        ahi, alo, pos_w, time_w, pol_w, partials);
    sign_reduce_kernel<<<DDIM / 256, 256, 0, stream>>>(partials, out);
}

// Round 8
// 821.473 us; speedup vs baseline: 1.1505x; 1.1505x over previous
//
#include <hip/hip_runtime.h>
#include <cstdint>
#include <cstddef>

#define MROWS 200            // T*C real rows
#define PM    224            // padded rows: 14 frag-rows of 16 (>= 200)
#define KDIM  16384          // H*W
#define DDIM  8192           // hypervector dim
#define KSL   8              // k slices (grid.x); 512 blocks = exactly 2/CU
#define KPER  (KDIM / KSL)   // 2048
#define BK    32
#define NSTEP (KPER / BK)    // 64 K-steps per block

typedef __bf16 bf16x8 __attribute__((ext_vector_type(8)));
typedef float  f32x4  __attribute__((ext_vector_type(4)));

static __device__ __forceinline__ unsigned short f2bf_rne(float f) {
    unsigned int u = __float_as_uint(f);
    unsigned int r = (u + 0x7FFFu + ((u >> 16) & 1u)) >> 16;
    return (unsigned short)r;
}
static __device__ __forceinline__ float bf2f(unsigned short s) {
    return __uint_as_float(((unsigned int)s) << 16);
}

// async global->LDS, 16B per lane; LDS dest is wave-uniform base + lane*16
static __device__ __forceinline__ void gld_lds16(const unsigned short* g,
                                                 unsigned short* l) {
    __builtin_amdgcn_global_load_lds(
        (const __attribute__((address_space(1))) unsigned int*)g,
        (__attribute__((address_space(3))) unsigned int*)l, 16, 0, 0);
}

// ---------------------------------------------------------------------------
// Prep: split hist fp32 -> (hi, lo) bf16 planes once. Rows [200,224) zeroed.
// 16B granules stored pre-swizzled within each 64B chunk (g ^= (m>>1)&3) so
// gemm's global_load_lds dest stays linear while frag reads de-swizzle.
// Replay-safe ws use: fully rewritten from inputs every launch.
// ---------------------------------------------------------------------------
__global__ __launch_bounds__(256) void prep_kernel(const float* __restrict__ hist,
                                                   unsigned short* __restrict__ ahi,
                                                   unsigned short* __restrict__ alo) {
    const int g  = blockIdx.x * 256 + threadIdx.x;   // granule id, < PM*2048
    const int m  = g >> 11;                          // 2048 granules per row
    const int gc = g & 2047;
    const int f  = (m >> 1) & 3;
    const int sgc = (gc & ~3) | ((gc & 3) ^ f);      // swizzled source granule
    alignas(16) unsigned short hi[8], lo[8];
    if (m < MROWS) {
        const float* src = hist + (size_t)m * KDIM + sgc * 8;
        float4 a = *(const float4*)(src);
        float4 b = *(const float4*)(src + 4);
        const float v[8] = {a.x, a.y, a.z, a.w, b.x, b.y, b.z, b.w};
#pragma unroll
        for (int i = 0; i < 8; ++i) {
            unsigned short h = f2bf_rne(v[i]);
            hi[i] = h;
            lo[i] = f2bf_rne(v[i] - bf2f(h));        // exact residual
        }
    } else {
#pragma unroll
        for (int i = 0; i < 8; ++i) { hi[i] = 0; lo[i] = 0; }
    }
    *(uint4*)(ahi + (size_t)g * 8) = *(const uint4*)hi;
    *(uint4*)(alo + (size_t)g * 8) = *(const uint4*)lo;
}

// ---------------------------------------------------------------------------
// Fused GEMM + bind-reduce, BM=224 x BN=128 x BK=32, single m-block.
// R8 = r5 (best, 726us, gemm ~159us = 756 TF) + ONE change: B prefetch
// depth 2 -> 4. Mechanism: at depth 2 each block's in-flight B collapses
// to ~0 once per step (right before pack), and the barrier cadence
// synchronizes these gaps chip-wide; depth 4 keeps ~48KB/block queued so
// HBM occupancy is decoupled from the barrier cadence.
// Ledger (re-derived, per wave, issue order per step kk = A(kk+1), B(kk+4)):
//   at BAR(kk) outstanding = B(kk+1)[kk-3], B(kk+2)[kk-2], A(kk)[kk-1],
//   B(kk+3)[kk-1, after A]  ->  newer-than-A = 4  ->  vmcnt(4) (unchanged).
//   pack B(kk) uses regs loaded at kk-4 (4 full steps of cover).
// One barrier per K-step (r5 safety argument unchanged):
//   - fb/fa ds_reads of step kk complete before that wave's MFMAs issue,
//     hence before BAR(kk+1), hence before pack(kk+2)/DMA(kk+2) rewrites.
//   - per-wave vmcnt(4) before BAR: wave's own A-DMAs landed; all waves
//     waiting => all 28 chunks landed at barrier release.
// Tail: A/B issues wrap via &(NSTEP-1) (dummy loads into buffers never
// read afterward; drained by the final __syncthreads).
// ---------------------------------------------------------------------------
__global__ __launch_bounds__(256, 2)
void gemm_kernel(const unsigned short* __restrict__ ahi,
                 const unsigned short* __restrict__ alo,
                 const float* __restrict__ pos,
                 const float* __restrict__ time_w,
                 const float* __restrict__ pol_w,
                 float* __restrict__ partials) {
    __shared__ alignas(16) unsigned short As[2][2][PM * BK]; // [buf][plane] 56KB
    __shared__ alignas(16) unsigned short Bs[2][128][40];    // dbuf, +8 pad 20KB
    __shared__ float sPart[128];

    const int t     = threadIdx.x;
    const int ks    = blockIdx.x;              // k-slice major: XCD = ks
    const int n0    = blockIdx.y * 128;
    const int kbase = ks * KPER;

    const int lane = t & 63;
    const int wv   = t >> 6;
    const int wm   = (wv & 1) * 112;           // 7 frag-rows per wave
    const int wn   = (wv >> 1) * 64;
    const int l15  = lane & 15;
    const int q8   = (lane >> 4) * 8;          // B k-granule offset
    const int qg   = (lane >> 4) ^ ((l15 >> 1) & 3);  // A de-swizzle granule

    if (t < 128) sPart[t] = 0.f;               // visible after BAR of step 0

    // A chunk assignment: 28 chunks (2 planes x 14 chunks of 16 rows), 7/wave.
    const int lr = lane >> 2, lg = lane & 3;
    const unsigned short* gA[7];
    unsigned short* lA[2][7];
#pragma unroll
    for (int i = 0; i < 7; ++i) {
        const int cc = wv * 7 + i;
        const int pl = (cc >= 14) ? 1 : 0;
        const int ch = cc - pl * 14;
        gA[i] = (pl ? alo : ahi) + (size_t)(ch * 16 + lr) * KDIM + kbase + lg * 8;
        lA[0][i] = &As[0][pl][ch * 512];       // wave-uniform LDS bases
        lA[1][i] = &As[1][pl][ch * 512];
    }

    // B map: thread -> (2 k-rows, 8 consecutive n)
    const int bk2 = (t & 15) * 2;
    const int bnb = (t >> 4) * 8;
    const float* gB0 = pos + ((size_t)kbase + bk2) * DDIM + n0 + bnb;
    const float* gB1 = gB0 + DDIM;

    f32x4 acc[7][4];
#pragma unroll
    for (int s = 0; s < 7; ++s)
#pragma unroll
        for (int j = 0; j < 4; ++j) acc[s][j] = (f32x4){0.f, 0.f, 0.f, 0.f};

    float4 br[4][4];                           // B regs, 4 steps deep (static idx)

    // ---- prologue: B(0);B(1);B(2); A(0); B(3). Order defines the ledger:
    // at BAR(0), newer-than-A(0) = B(3)'s 4 loads -> vmcnt(4). ----
#pragma unroll
    for (int p = 0; p < 3; ++p) {
        const size_t roff = (size_t)p * BK * DDIM;
        br[p][0] = *(const float4*)(gB0 + roff);
        br[p][1] = *(const float4*)(gB0 + roff + 4);
        br[p][2] = *(const float4*)(gB1 + roff);
        br[p][3] = *(const float4*)(gB1 + roff + 4);
        __builtin_amdgcn_sched_barrier(0);
    }
#pragma unroll
    for (int i = 0; i < 7; ++i) gld_lds16(gA[i], lA[0][i]);
    __builtin_amdgcn_sched_barrier(0);
    {
        const size_t r3 = (size_t)3 * BK * DDIM;
        br[3][0] = *(const float4*)(gB0 + r3);
        br[3][1] = *(const float4*)(gB0 + r3 + 4);
        br[3][2] = *(const float4*)(gB1 + r3);
        br[3][3] = *(const float4*)(gB1 + r3 + 4);
    }
    __builtin_amdgcn_sched_barrier(0);

    for (int kp = 0; kp < NSTEP; kp += 4) {
#pragma unroll
        for (int u = 0; u < 4; ++u) {
            const int kk = kp + u;             // br slot = kk&3, LDS buf = kk&1
            const int b  = kk & 1;

            // ---- pack B(kk) (4-step-old regs) into Bs[b] ----
            {
                const float xv[8] = {br[u][0].x, br[u][0].y, br[u][0].z, br[u][0].w,
                                     br[u][1].x, br[u][1].y, br[u][1].z, br[u][1].w};
                const float yv[8] = {br[u][2].x, br[u][2].y, br[u][2].z, br[u][2].w,
                                     br[u][3].x, br[u][3].y, br[u][3].z, br[u][3].w};
#pragma unroll
                for (int j = 0; j < 8; ++j) {
                    unsigned int w = (__float_as_uint(xv[j]) >> 16) |
                                     (__float_as_uint(yv[j]) & 0xFFFF0000u);
                    *(unsigned int*)&Bs[b][bnb + j][bk2] = w;
                }
            }
            __builtin_amdgcn_sched_barrier(0);
            // Wave's A(kk) landed (leave the 4 newer B(kk+3) loads in
            // flight), Bs[b] writes drained -> ONE barrier: tiles(kk) ready.
            asm volatile("s_waitcnt vmcnt(4) lgkmcnt(0)" ::: "memory");
            __builtin_amdgcn_s_barrier();                       // the only BAR
            __builtin_amdgcn_sched_barrier(0);

            // ---- issue A(kk+1) into the other LDS buffer ----
            {
                const int koff = ((kk + 1) & (NSTEP - 1)) * BK; // ushorts
#pragma unroll
                for (int i = 0; i < 7; ++i)
                    gld_lds16(gA[i] + koff, lA[b ^ 1][i]);
            }
            __builtin_amdgcn_sched_barrier(0);

            // ---- issue B(kk+4) into br[u] (wrapped dummies at tail) ----
            {
                const size_t roff = (size_t)((kk + 4) & (NSTEP - 1)) * BK * DDIM;
                br[u][0] = *(const float4*)(gB0 + roff);
                br[u][1] = *(const float4*)(gB0 + roff + 4);
                br[u][2] = *(const float4*)(gB1 + roff);
                br[u][3] = *(const float4*)(gB1 + roff + 4);
            }
            __builtin_amdgcn_sched_barrier(0);

            // ---- fragments + MFMA on tiles(kk) ----
            uint4 fb[4];
#pragma unroll
            for (int j = 0; j < 4; ++j)
                fb[j] = *(const uint4*)&Bs[b][wn + j * 16 + l15][q8];

            __builtin_amdgcn_s_setprio(1);
#pragma unroll
            for (int s = 0; s < 7; ++s) {
                const int mo = (wm + s * 16 + l15) * 32 + qg * 8;
                const uint4 fa0 = *(const uint4*)&As[b][0][mo];
                const uint4 fa1 = *(const uint4*)&As[b][1][mo];
#pragma unroll
                for (int j = 0; j < 4; ++j)    // hi plane: 4 independent
                    acc[s][j] = __builtin_amdgcn_mfma_f32_16x16x32_bf16(
                        __builtin_bit_cast(bf16x8, fa0),
                        __builtin_bit_cast(bf16x8, fb[j]), acc[s][j], 0, 0, 0);
#pragma unroll
                for (int j = 0; j < 4; ++j)    // lo plane
                    acc[s][j] = __builtin_amdgcn_mfma_f32_16x16x32_bf16(
                        __builtin_bit_cast(bf16x8, fa1),
                        __builtin_bit_cast(bf16x8, fb[j]), acc[s][j], 0, 0, 0);
            }
            __builtin_amdgcn_s_setprio(0);
            __builtin_amdgcn_sched_barrier(0);
        }
    }

    // Epilogue: C/D layout col = lane&15, row = (lane>>4)*4 + reg (m89/m91).
    // Block owns partial strip (ks, n0..n0+127) exclusively -> plain store.
    const int qrow = (lane >> 4) * 4;
#pragma unroll
    for (int j = 0; j < 4; ++j) {
        const int col = wn + j * 16 + l15;
        const int d   = n0 + col;
        const float p0 = pol_w[d];
        const float p1 = pol_w[DDIM + d];
        float part = 0.f;
#pragma unroll
        for (int s = 0; s < 7; ++s)
#pragma unroll
            for (int r = 0; r < 4; ++r) {
                const int m = wm + s * 16 + qrow + r;
                if (m < MROWS) {               // pad rows: zero A, skip weights
                    const float w = time_w[(size_t)(m >> 1) * DDIM + d] *
                                    ((m & 1) ? p1 : p0);
                    part += w * acc[s][j][r];
                }
            }
        atomicAdd(&sPart[col], part);          // LDS-scope only (2 m-waves/col)
    }
    __syncthreads();                           // drains leftover dummy loads
    if (t < 128) partials[(size_t)ks * DDIM + n0 + t] = sPart[t];
}

// ---------------------------------------------------------------------------
// Final: out[d] = sign(sum_ks partials[ks][d]). Writes every element of out.
// ---------------------------------------------------------------------------
__global__ __launch_bounds__(256) void sign_reduce_kernel(const float* __restrict__ partials,
                                                          float* __restrict__ out) {
    const int d = blockIdx.x * 256 + threadIdx.x;
    float s = 0.f;
#pragma unroll
    for (int k = 0; k < KSL; ++k) s += partials[(size_t)k * DDIM + d];
    out[d] = (s > 0.f) ? 1.f : ((s < 0.f) ? -1.f : 0.f);
}

// ---------------------------------------------------------------------------
extern "C" void kernel_launch(void* const* d_in, const int* in_sizes, int n_in,
                              void* d_out, int out_size, void* d_ws, size_t ws_size,
                              hipStream_t stream) {
    const float* hist   = (const float*)d_in[0];   // [100,2,128,128]
    const float* time_w = (const float*)d_in[1];   // [100,8192]
    const float* pol_w  = (const float*)d_in[2];   // [2,8192]
    const float* pos_w  = (const float*)d_in[3];   // [16384,8192]
    float* out = (float*)d_out;                    // [8192]

    unsigned short* ahi = (unsigned short*)d_ws;               // 7.34 MB
    unsigned short* alo = ahi + (size_t)PM * KDIM;             // 7.34 MB
    float* partials = (float*)(alo + (size_t)PM * KDIM);       // 256 KB
    (void)in_sizes; (void)n_in; (void)out_size; (void)ws_size; // ws >= 15 MB

    prep_kernel<<<(PM * (KDIM / 8)) / 256, 256, 0, stream>>>(hist, ahi, alo);
    gemm_kernel<<<dim3(KSL, DDIM / 128), 256, 0, stream>>>(ahi, alo, pos_w,
                                                           time_w, pol_w, partials);
    sign_reduce_kernel<<<DDIM / 256, 256, 0, stream>>>(partials, out);
}

// Round 9
// 722.149 us; speedup vs baseline: 1.3087x; 1.1375x over previous
//
#include <hip/hip_runtime.h>
#include <cstdint>
#include <cstddef>

#define MROWS 200            // T*C real rows
#define PM    224            // padded rows: 14 frag-rows of 16 (>= 200)
#define KDIM  16384          // H*W
#define DDIM  8192           // hypervector dim
#define KSL   8              // k slices (grid.x); 512 blocks = exactly 2/CU
#define KPER  (KDIM / KSL)   // 2048
#define BK    32
#define NSTEP (KPER / BK)    // 64 K-steps per block

typedef __bf16 bf16x8 __attribute__((ext_vector_type(8)));
typedef float  f32x4  __attribute__((ext_vector_type(4)));

static __device__ __forceinline__ unsigned short f2bf_rne(float f) {
    unsigned int u = __float_as_uint(f);
    unsigned int r = (u + 0x7FFFu + ((u >> 16) & 1u)) >> 16;
    return (unsigned short)r;
}
static __device__ __forceinline__ float bf2f(unsigned short s) {
    return __uint_as_float(((unsigned int)s) << 16);
}

// async global->LDS, 16B per lane; LDS dest is wave-uniform base + lane*16
static __device__ __forceinline__ void gld_lds16(const unsigned short* g,
                                                 unsigned short* l) {
    __builtin_amdgcn_global_load_lds(
        (const __attribute__((address_space(1))) unsigned int*)g,
        (__attribute__((address_space(3))) unsigned int*)l, 16, 0, 0);
}

// ---------------------------------------------------------------------------
// Prep: split hist fp32 -> (hi, lo) bf16 planes once. Rows [200,224) zeroed.
// 16B granules stored pre-swizzled within each 64B chunk (g ^= (m>>1)&3) so
// gemm's global_load_lds dest stays linear while frag reads de-swizzle.
// Replay-safe ws use: fully rewritten from inputs every launch.
// ---------------------------------------------------------------------------
__global__ __launch_bounds__(256) void prep_kernel(const float* __restrict__ hist,
                                                   unsigned short* __restrict__ ahi,
                                                   unsigned short* __restrict__ alo) {
    const int g  = blockIdx.x * 256 + threadIdx.x;   // granule id, < PM*2048
    const int m  = g >> 11;                          // 2048 granules per row
    const int gc = g & 2047;
    const int f  = (m >> 1) & 3;
    const int sgc = (gc & ~3) | ((gc & 3) ^ f);      // swizzled source granule
    alignas(16) unsigned short hi[8], lo[8];
    if (m < MROWS) {
        const float* src = hist + (size_t)m * KDIM + sgc * 8;
        float4 a = *(const float4*)(src);
        float4 b = *(const float4*)(src + 4);
        const float v[8] = {a.x, a.y, a.z, a.w, b.x, b.y, b.z, b.w};
#pragma unroll
        for (int i = 0; i < 8; ++i) {
            unsigned short h = f2bf_rne(v[i]);
            hi[i] = h;
            lo[i] = f2bf_rne(v[i] - bf2f(h));        // exact residual
        }
    } else {
#pragma unroll
        for (int i = 0; i < 8; ++i) { hi[i] = 0; lo[i] = 0; }
    }
    *(uint4*)(ahi + (size_t)g * 8) = *(const uint4*)hi;
    *(uint4*)(alo + (size_t)g * 8) = *(const uint4*)lo;
}

// ---------------------------------------------------------------------------
// Fused GEMM + bind-reduce, BM=224 x BN=128 x BK=32, single m-block.
// R9 = exact revert to the r5 configuration — the session's verified best
// (726us total; gemm ~159us = 756 TF ~= 30% dense peak, m97-class).
// Verified-from-both-sides local optimum:
//   barrier/step: 2 (r2, null) -> 1 (r5, -30us) ; wider blocks (r6, +23)
//   blocks/CU:    2 -> 3 via plane-split (r7, +219)
//   B depth:      2 -> 4 (r8, +95: +32 VGPR -> ~256-cap edge, no gain at
//                 the barrier since FIFO vmcnt already left only B(kk+1))
// ONE barrier per K-step; counted vmcnt, never 0 in the main loop:
//   - fb/fa ds_reads of step kk complete before that wave's MFMAs issue,
//     hence before BAR(kk+1), hence before pack(kk+2)/DMA(kk+2) rewrites.
//   - per-wave vmcnt(4) before BAR: wave's own A-DMAs landed (leaves the
//     4 newer B(kk+1) loads in flight); all waves waiting => all 28 chunks
//     landed at barrier release.
// Step kk: pack Bs[u]<-br[u]; vmcnt(4)+lgkm(0)+BAR; issue A(kk+1)->As[u^1];
//          issue B(kk+2)->br[u]; fb/fa ds_reads; 56 MFMA (setprio 1).
// Tail issues wrap via &(NSTEP-1) (dummy loads into never-read buffers;
// drained by the final __syncthreads).
// KSL=8: 512 blocks = exactly 2/CU, one residency round, XCD = ks so the
// A slice (1.84 MB) is L2-resident per XCD. LDS = 56+20.5+0.5 = 77 KB.
// Remaining total is dominated by the measured ~567us harness floor
// (2-GiB ws-poison fill ~335us + ~220us reset/launch dispatches).
// ---------------------------------------------------------------------------
__global__ __launch_bounds__(256, 2)
void gemm_kernel(const unsigned short* __restrict__ ahi,
                 const unsigned short* __restrict__ alo,
                 const float* __restrict__ pos,
                 const float* __restrict__ time_w,
                 const float* __restrict__ pol_w,
                 float* __restrict__ partials) {
    __shared__ alignas(16) unsigned short As[2][2][PM * BK]; // [buf][plane] 56KB
    __shared__ alignas(16) unsigned short Bs[2][128][40];    // dbuf, +8 pad 20KB
    __shared__ float sPart[128];

    const int t     = threadIdx.x;
    const int ks    = blockIdx.x;              // k-slice major: XCD = ks
    const int n0    = blockIdx.y * 128;
    const int kbase = ks * KPER;

    const int lane = t & 63;
    const int wv   = t >> 6;
    const int wm   = (wv & 1) * 112;           // 7 frag-rows per wave
    const int wn   = (wv >> 1) * 64;
    const int l15  = lane & 15;
    const int q8   = (lane >> 4) * 8;          // B k-granule offset
    const int qg   = (lane >> 4) ^ ((l15 >> 1) & 3);  // A de-swizzle granule

    if (t < 128) sPart[t] = 0.f;               // visible after BAR of step 0

    // A chunk assignment: 28 chunks (2 planes x 14 chunks of 16 rows), 7/wave.
    const int lr = lane >> 2, lg = lane & 3;
    const unsigned short* gA[7];
    unsigned short* lA[2][7];
#pragma unroll
    for (int i = 0; i < 7; ++i) {
        const int cc = wv * 7 + i;
        const int pl = (cc >= 14) ? 1 : 0;
        const int ch = cc - pl * 14;
        gA[i] = (pl ? alo : ahi) + (size_t)(ch * 16 + lr) * KDIM + kbase + lg * 8;
        lA[0][i] = &As[0][pl][ch * 512];       // wave-uniform LDS bases
        lA[1][i] = &As[1][pl][ch * 512];
    }

    // B map: thread -> (2 k-rows, 8 consecutive n)
    const int bk2 = (t & 15) * 2;
    const int bnb = (t >> 4) * 8;
    const float* gB0 = pos + ((size_t)kbase + bk2) * DDIM + n0 + bnb;
    const float* gB1 = gB0 + DDIM;

    f32x4 acc[7][4];
#pragma unroll
    for (int s = 0; s < 7; ++s)
#pragma unroll
        for (int j = 0; j < 4; ++j) acc[s][j] = (f32x4){0.f, 0.f, 0.f, 0.f};

    float4 br[2][4];                           // B regs, 2 steps deep

    // ---- prologue: B(0); A(0)->buf0; B(1). Order defines the ledger:
    // at BAR(0), loads newer than A(0) = B(1) = 4 -> vmcnt(4). ----
    br[0][0] = *(const float4*)(gB0);
    br[0][1] = *(const float4*)(gB0 + 4);
    br[0][2] = *(const float4*)(gB1);
    br[0][3] = *(const float4*)(gB1 + 4);
    __builtin_amdgcn_sched_barrier(0);
#pragma unroll
    for (int i = 0; i < 7; ++i) gld_lds16(gA[i], lA[0][i]);
    __builtin_amdgcn_sched_barrier(0);
    {
        const size_t r1 = (size_t)BK * DDIM;
        br[1][0] = *(const float4*)(gB0 + r1);
        br[1][1] = *(const float4*)(gB0 + r1 + 4);
        br[1][2] = *(const float4*)(gB1 + r1);
        br[1][3] = *(const float4*)(gB1 + r1 + 4);
    }
    __builtin_amdgcn_sched_barrier(0);

    for (int kp = 0; kp < NSTEP; kp += 2) {
#pragma unroll
        for (int u = 0; u < 2; ++u) {
            const int kk = kp + u;             // br/buf parity == u

            // ---- pack B(kk) (2-step-old regs) into Bs[u] ----
            {
                const float xv[8] = {br[u][0].x, br[u][0].y, br[u][0].z, br[u][0].w,
                                     br[u][1].x, br[u][1].y, br[u][1].z, br[u][1].w};
                const float yv[8] = {br[u][2].x, br[u][2].y, br[u][2].z, br[u][2].w,
                                     br[u][3].x, br[u][3].y, br[u][3].z, br[u][3].w};
#pragma unroll
                for (int j = 0; j < 8; ++j) {
                    unsigned int w = (__float_as_uint(xv[j]) >> 16) |
                                     (__float_as_uint(yv[j]) & 0xFFFF0000u);
                    *(unsigned int*)&Bs[u][bnb + j][bk2] = w;
                }
            }
            __builtin_amdgcn_sched_barrier(0);
            // A(kk) landed (leave the 4 newer B(kk+1) loads in flight),
            // Bs[u] writes drained -> ONE barrier: tiles(kk) ready.
            asm volatile("s_waitcnt vmcnt(4) lgkmcnt(0)" ::: "memory");
            __builtin_amdgcn_s_barrier();                       // the only BAR
            __builtin_amdgcn_sched_barrier(0);

            // ---- issue A(kk+1) into the other LDS buffer ----
            {
                const int koff = ((kk + 1) & (NSTEP - 1)) * BK; // ushorts
#pragma unroll
                for (int i = 0; i < 7; ++i)
                    gld_lds16(gA[i] + koff, lA[u ^ 1][i]);
            }
            __builtin_amdgcn_sched_barrier(0);

            // ---- issue B(kk+2) into br[u] EARLY (wrapped dummies at tail) ----
            {
                const size_t roff = (size_t)((kk + 2) & (NSTEP - 1)) * BK * DDIM;
                br[u][0] = *(const float4*)(gB0 + roff);
                br[u][1] = *(const float4*)(gB0 + roff + 4);
                br[u][2] = *(const float4*)(gB1 + roff);
                br[u][3] = *(const float4*)(gB1 + roff + 4);
            }
            __builtin_amdgcn_sched_barrier(0);

            // ---- fragments + MFMA on tiles(kk) ----
            uint4 fb[4];
#pragma unroll
            for (int j = 0; j < 4; ++j)
                fb[j] = *(const uint4*)&Bs[u][wn + j * 16 + l15][q8];

            __builtin_amdgcn_s_setprio(1);
#pragma unroll
            for (int s = 0; s < 7; ++s) {
                const int mo = (wm + s * 16 + l15) * 32 + qg * 8;
                const uint4 fa0 = *(const uint4*)&As[u][0][mo];
                const uint4 fa1 = *(const uint4*)&As[u][1][mo];
#pragma unroll
                for (int j = 0; j < 4; ++j)    // hi plane: 4 independent
                    acc[s][j] = __builtin_amdgcn_mfma_f32_16x16x32_bf16(
                        __builtin_bit_cast(bf16x8, fa0),
                        __builtin_bit_cast(bf16x8, fb[j]), acc[s][j], 0, 0, 0);
#pragma unroll
                for (int j = 0; j < 4; ++j)    // lo plane
                    acc[s][j] = __builtin_amdgcn_mfma_f32_16x16x32_bf16(
                        __builtin_bit_cast(bf16x8, fa1),
                        __builtin_bit_cast(bf16x8, fb[j]), acc[s][j], 0, 0, 0);
            }
            __builtin_amdgcn_s_setprio(0);
            __builtin_amdgcn_sched_barrier(0);
        }
    }

    // Epilogue: C/D layout col = lane&15, row = (lane>>4)*4 + reg (m89/m91).
    // Block owns partial strip (ks, n0..n0+127) exclusively -> plain store.
    const int qrow = (lane >> 4) * 4;
#pragma unroll
    for (int j = 0; j < 4; ++j) {
        const int col = wn + j * 16 + l15;
        const int d   = n0 + col;
        const float p0 = pol_w[d];
        const float p1 = pol_w[DDIM + d];
        float part = 0.f;
#pragma unroll
        for (int s = 0; s < 7; ++s)
#pragma unroll
            for (int r = 0; r < 4; ++r) {
                const int m = wm + s * 16 + qrow + r;
                if (m < MROWS) {               // pad rows: zero A, skip weights
                    const float w = time_w[(size_t)(m >> 1) * DDIM + d] *
                                    ((m & 1) ? p1 : p0);
                    part += w * acc[s][j][r];
                }
            }
        atomicAdd(&sPart[col], part);          // LDS-scope only (2 m-waves/col)
    }
    __syncthreads();                           // drains leftover dummy loads
    if (t < 128) partials[(size_t)ks * DDIM + n0 + t] = sPart[t];
}

// ---------------------------------------------------------------------------
// Final: out[d] = sign(sum_ks partials[ks][d]). Writes every element of out.
// ---------------------------------------------------------------------------
__global__ __launch_bounds__(256) void sign_reduce_kernel(const float* __restrict__ partials,
                                                          float* __restrict__ out) {
    const int d = blockIdx.x * 256 + threadIdx.x;
    float s = 0.f;
#pragma unroll
    for (int k = 0; k < KSL; ++k) s += partials[(size_t)k * DDIM + d];
    out[d] = (s > 0.f) ? 1.f : ((s < 0.f) ? -1.f : 0.f);
}

// ---------------------------------------------------------------------------
extern "C" void kernel_launch(void* const* d_in, const int* in_sizes, int n_in,
                              void* d_out, int out_size, void* d_ws, size_t ws_size,
                              hipStream_t stream) {
    const float* hist   = (const float*)d_in[0];   // [100,2,128,128]
    const float* time_w = (const float*)d_in[1];   // [100,8192]
    const float* pol_w  = (const float*)d_in[2];   // [2,8192]
    const float* pos_w  = (const float*)d_in[3];   // [16384,8192]
    float* out = (float*)d_out;                    // [8192]

    unsigned short* ahi = (unsigned short*)d_ws;               // 7.34 MB
    unsigned short* alo = ahi + (size_t)PM * KDIM;             // 7.34 MB
    float* partials = (float*)(alo + (size_t)PM * KDIM);       // 256 KB
    (void)in_sizes; (void)n_in; (void)out_size; (void)ws_size; // ws >= 15 MB

    prep_kernel<<<(PM * (KDIM / 8)) / 256, 256, 0, stream>>>(hist, ahi, alo);
    gemm_kernel<<<dim3(KSL, DDIM / 128), 256, 0, stream>>>(ahi, alo, pos_w,
                                                           time_w, pol_w, partials);
    sign_reduce_kernel<<<DDIM / 256, 256, 0, stream>>>(partials, out);
}